// Round 1
// baseline (57.174 us; speedup 1.0000x reference)
//
#include <hip/hip_runtime.h>
#include <stdint.h>

// Chamfer L1, B=4, N=M=8192, 3-D points.
// Quantize coords to u16 fixed point (4096 steps/unit, +8 offset), then
// per point-pair distance = 2x v_sad_u16 + 1x v_min_u32 (3 VALU ops/pair).

#define BATCH   4
#define NPTS    8192
#define QPB     64          // query points per block
#define THREADS 256         // 4 waves
#define NCHUNK  4           // one ref-chunk per wave
#define CHUNK   (NPTS / NCHUNK)   // 2048
#define TILE    1024              // points per chunk per staging round
#define NTILE   (CHUNK / TILE)    // 2
#define QSCALE  4096.0f
#define QOFFS   8.0f

static __device__ __forceinline__ uint32_t sad_u16(uint32_t a, uint32_t b, uint32_t c) {
#if __has_builtin(__builtin_amdgcn_sad_u16)
    return __builtin_amdgcn_sad_u16(a, b, c);
#else
    uint32_t d;
    asm("v_sad_u16 %0, %1, %2, %3" : "=v"(d) : "v"(a), "v"(b), "v"(c));
    return d;
#endif
}

static __device__ __forceinline__ uint32_t umin32(uint32_t a, uint32_t b) {
    return a < b ? a : b;
}

static __device__ __forceinline__ uint32_t quant(float x) {
    float v = (x + QOFFS) * QSCALE;
    v = fminf(fmaxf(v, 0.0f), 65535.0f);
    return (uint32_t)(v + 0.5f);
}

__global__ __launch_bounds__(THREADS, 4) void chamfer_l1_kernel(
    const float* __restrict__ pred, const float* __restrict__ target,
    float* __restrict__ out)
{
    __shared__ __align__(16) uint2 tile[NCHUNK][TILE];   // 32 KiB
    __shared__ uint32_t sbest[THREADS];                  // 1 KiB

    const int t    = threadIdx.x;
    const int lane = t & 63;
    const int wave = t >> 6;
    const int qblock = blockIdx.x;          // 0..127
    const int dirb   = blockIdx.y;          // 0..7
    const int dir    = dirb >> 2;           // 0: pred->target, 1: target->pred
    const int b      = dirb & 3;

    const float* qbase = (dir == 0 ? pred : target) + (size_t)b * NPTS * 3;
    const float* rbase = (dir == 0 ? target : pred) + (size_t)b * NPTS * 3;

    // my query point (each query handled by 4 threads, one per wave)
    const int qi = qblock * QPB + lane;
    const float* qp = qbase + (size_t)qi * 3;
    const uint32_t qxy = quant(qp[0]) | (quant(qp[1]) << 16);
    const uint32_t qz  = quant(qp[2]);

    uint32_t best0 = 0xFFFFFFFFu, best1 = 0xFFFFFFFFu;
    uint32_t best2 = 0xFFFFFFFFu, best3 = 0xFFFFFFFFu;

    for (int ti = 0; ti < NTILE; ++ti) {
        __syncthreads();   // previous-tile readers done
        // stage 4 chunks x TILE points, quantized, packed
        #pragma unroll
        for (int k = 0; k < (NCHUNK * TILE) / THREADS; ++k) {   // 16 pts/thread
            int idx = t + k * THREADS;           // 0..4095
            int c   = idx >> 10;                 // / TILE
            int pos = idx & (TILE - 1);
            int pt  = c * CHUNK + ti * TILE + pos;
            const float* rp = rbase + (size_t)pt * 3;
            tile[c][pos] = make_uint2(quant(rp[0]) | (quant(rp[1]) << 16),
                                      quant(rp[2]));
        }
        __syncthreads();

        // wave w scans its own chunk's tile; all lanes read the same address
        // (LDS broadcast, conflict-free), 2 points per ds_read_b128
        const uint4* tp = reinterpret_cast<const uint4*>(&tile[wave][0]);
        #pragma unroll 8
        for (int j = 0; j < TILE / 2; j += 2) {
            uint4 v0 = tp[j];
            uint4 v1 = tp[j + 1];
            uint32_t d0 = sad_u16(v0.y, qz, sad_u16(v0.x, qxy, 0u));
            uint32_t d1 = sad_u16(v0.w, qz, sad_u16(v0.z, qxy, 0u));
            uint32_t d2 = sad_u16(v1.y, qz, sad_u16(v1.x, qxy, 0u));
            uint32_t d3 = sad_u16(v1.w, qz, sad_u16(v1.z, qxy, 0u));
            best0 = umin32(best0, d0);
            best1 = umin32(best1, d1);
            best2 = umin32(best2, d2);
            best3 = umin32(best3, d3);
        }
    }

    uint32_t best = umin32(umin32(best0, best1), umin32(best2, best3));

    // cross-wave min per query, then block sum, one atomicAdd per block
    __syncthreads();
    sbest[t] = best;
    __syncthreads();

    if (t < 64) {
        uint32_t m = umin32(umin32(sbest[t], sbest[t + 64]),
                            umin32(sbest[t + 128], sbest[t + 192]));
        float fm = (float)m * (1.0f / QSCALE);
        #pragma unroll
        for (int off = 32; off > 0; off >>= 1)
            fm += __shfl_down(fm, off);
        if (t == 0)
            atomicAdd(out, fm * (1.0f / (float)BATCH));
    }
}

extern "C" void kernel_launch(void* const* d_in, const int* in_sizes, int n_in,
                              void* d_out, int out_size, void* d_ws, size_t ws_size,
                              hipStream_t stream) {
    const float* pred   = (const float*)d_in[0];
    const float* target = (const float*)d_in[1];
    float* out = (float*)d_out;

    // harness poisons d_out once and never re-poisons: zero it every call
    hipMemsetAsync(out, 0, sizeof(float), stream);

    dim3 grid(NPTS / QPB, 2 * BATCH);   // 128 x 8 = 1024 blocks, 4 waves each
    chamfer_l1_kernel<<<grid, THREADS, 0, stream>>>(pred, target, out);
}

// Round 2
// 54.773 us; speedup vs baseline: 1.0438x; 1.0438x over previous
//
#include <hip/hip_runtime.h>
#include <stdint.h>

// Chamfer L1, B=4, N=M=8192, 3-D points.
// u16 fixed-point quantization (4096/unit, +8 offset):
//   pair distance = 2x v_sad_u16, accumulate min via v_min3_u32
//   => 2.5 VALU ops/pair. 4 queries per lane amortize LDS broadcasts 4x.
// Stage 1: blocks of (1024 queries x 512-ref chunk) write per-chunk u16 mins to ws.
// Stage 2: reduce kernel mins over 16 chunks, sums, scales.

#define BATCH    4
#define NPTS     8192
#define QSCALE   4096.0f
#define QOFFS    8.0f
#define NCHUNK   16
#define CHUNKPTS (NPTS / NCHUNK)   // 512 refs per block
#define THREADS  256
#define QPL      4                 // queries per lane
#define QPB      (THREADS * QPL)   // 1024 queries per block

static __device__ __forceinline__ uint32_t sad_u16(uint32_t a, uint32_t b, uint32_t c) {
#if __has_builtin(__builtin_amdgcn_sad_u16)
    return __builtin_amdgcn_sad_u16(a, b, c);
#else
    uint32_t d;
    asm("v_sad_u16 %0, %1, %2, %3" : "=v"(d) : "v"(a), "v"(b), "v"(c));
    return d;
#endif
}

static __device__ __forceinline__ uint32_t min3_u32(uint32_t a, uint32_t b, uint32_t c) {
    uint32_t d;
    asm("v_min3_u32 %0, %1, %2, %3" : "=v"(d) : "v"(a), "v"(b), "v"(c));
    return d;
}

static __device__ __forceinline__ uint32_t umin32(uint32_t a, uint32_t b) {
    return a < b ? a : b;
}

static __device__ __forceinline__ uint32_t quant(float x) {
    float v = (x + QOFFS) * QSCALE;
    v = fminf(fmaxf(v, 0.0f), 65535.0f);
    return (uint32_t)(v + 0.5f);
}

__global__ __launch_bounds__(THREADS, 4) void chamfer_partial_kernel(
    const float* __restrict__ pred, const float* __restrict__ target,
    uint16_t* __restrict__ part)
{
    __shared__ __align__(16) uint2 tile[CHUNKPTS];   // 4 KiB

    const int t    = threadIdx.x;
    const int qg   = blockIdx.x >> 4;     // query group 0..7
    const int c    = blockIdx.x & 15;     // ref chunk   0..15
    const int dirb = blockIdx.y;          // 0..7
    const int dir  = dirb >> 2;           // 0: pred->target, 1: target->pred
    const int b    = dirb & 3;

    const float* qbase = (dir == 0 ? pred : target) + (size_t)b * NPTS * 3;
    const float* rbase = (dir == 0 ? target : pred) + (size_t)b * NPTS * 3;

    // stage this block's 512-ref chunk, quantized+packed (2 pts/thread)
    #pragma unroll
    for (int k = 0; k < CHUNKPTS / THREADS; ++k) {
        int pos = t + k * THREADS;
        const float* rp = rbase + (size_t)(c * CHUNKPTS + pos) * 3;
        tile[pos] = make_uint2(quant(rp[0]) | (quant(rp[1]) << 16), quant(rp[2]));
    }

    // load my 4 queries
    uint32_t qxy[QPL], qz[QPL], best[QPL];
    #pragma unroll
    for (int k = 0; k < QPL; ++k) {
        int q = qg * QPB + k * THREADS + t;
        const float* qp = qbase + (size_t)q * 3;
        qxy[k]  = quant(qp[0]) | (quant(qp[1]) << 16);
        qz[k]   = quant(qp[2]);
        best[k] = 0xFFFFFFFFu;
    }
    __syncthreads();

    // scan: one broadcast ds_read_b128 = 2 points, used by 4 queries
    const uint4* tp = reinterpret_cast<const uint4*>(tile);
    #pragma unroll 4
    for (int j = 0; j < CHUNKPTS / 2; ++j) {
        uint4 v = tp[j];
        #pragma unroll
        for (int k = 0; k < QPL; ++k) {
            uint32_t d0 = sad_u16(v.y, qz[k], sad_u16(v.x, qxy[k], 0u));
            uint32_t d1 = sad_u16(v.w, qz[k], sad_u16(v.z, qxy[k], 0u));
            best[k] = min3_u32(d0, d1, best[k]);
        }
    }

    // per-(query, chunk) partial min -> ws (u16: mins are << 65535)
    uint16_t* dst = part + ((size_t)(dirb * NCHUNK + c)) * NPTS + qg * QPB + t;
    #pragma unroll
    for (int k = 0; k < QPL; ++k)
        dst[k * THREADS] = (uint16_t)best[k];
}

__global__ __launch_bounds__(256) void chamfer_reduce_kernel(
    const uint16_t* __restrict__ part, float* __restrict__ out)
{
    const int tid = blockIdx.x * 256 + threadIdx.x;   // 8192 threads
    float fsum = 0.0f;
    #pragma unroll
    for (int i = 0; i < 8; ++i) {
        int idx  = tid + i * 8192;        // 0..65535 query slots
        int dirb = idx >> 13;
        int qi   = idx & (NPTS - 1);
        const uint16_t* p = part + (size_t)dirb * NCHUNK * NPTS + qi;
        uint32_t m = 0xFFFFFFFFu;
        #pragma unroll
        for (int cc = 0; cc < NCHUNK; ++cc)
            m = umin32(m, (uint32_t)p[cc * NPTS]);
        fsum += (float)m;
    }
    #pragma unroll
    for (int off = 32; off > 0; off >>= 1)
        fsum += __shfl_down(fsum, off);
    if ((threadIdx.x & 63) == 0)
        atomicAdd(out, fsum * (1.0f / (QSCALE * (float)BATCH)));
}

extern "C" void kernel_launch(void* const* d_in, const int* in_sizes, int n_in,
                              void* d_out, int out_size, void* d_ws, size_t ws_size,
                              hipStream_t stream) {
    const float* pred   = (const float*)d_in[0];
    const float* target = (const float*)d_in[1];
    float* out = (float*)d_out;
    uint16_t* part = (uint16_t*)d_ws;   // 8 dirb x 16 chunks x 8192 x u16 = 2 MiB

    hipMemsetAsync(out, 0, sizeof(float), stream);   // out is atomicAdd-accumulated

    dim3 grid(8 * NCHUNK, 2 * BATCH);   // 128 x 8 = 1024 blocks
    chamfer_partial_kernel<<<grid, THREADS, 0, stream>>>(pred, target, part);
    chamfer_reduce_kernel<<<32, 256, 0, stream>>>(part, out);
}

// Round 3
// 54.633 us; speedup vs baseline: 1.0465x; 1.0025x over previous
//
#include <hip/hip_runtime.h>
#include <stdint.h>

// Chamfer L1, B=4, N=M=8192, 3-D points.
// u16 fixed-point quantization (4096/unit, +8 offset):
//   pair distance = 2x v_sad_u16 (half-rate: 4cyc), min via v_min3_u32.
// VALU floor = 8.39M wave-pairs x 9 cyc / 1024 SIMDs = 30.7 us.
// 2048 blocks (8/CU -> 8 waves/SIMD) to saturate VALU; per-chunk mins
// combined via global atomicMin into 256 KB ws, then a tiny sum kernel.

#define BATCH    4
#define NPTS     8192
#define QSCALE   4096.0f
#define QOFFS    8.0f
#define NCHUNK   32
#define CHUNKPTS (NPTS / NCHUNK)   // 256 refs per block
#define THREADS  256
#define QPL      4                 // queries per lane
#define QPB      (THREADS * QPL)   // 1024 queries per block
#define NQG      (NPTS / QPB)      // 8 query groups

static __device__ __forceinline__ uint32_t sad_u16(uint32_t a, uint32_t b, uint32_t c) {
#if __has_builtin(__builtin_amdgcn_sad_u16)
    return __builtin_amdgcn_sad_u16(a, b, c);
#else
    uint32_t d;
    asm("v_sad_u16 %0, %1, %2, %3" : "=v"(d) : "v"(a), "v"(b), "v"(c));
    return d;
#endif
}

static __device__ __forceinline__ uint32_t min3_u32(uint32_t a, uint32_t b, uint32_t c) {
    uint32_t d;
    asm("v_min3_u32 %0, %1, %2, %3" : "=v"(d) : "v"(a), "v"(b), "v"(c));
    return d;
}

static __device__ __forceinline__ uint32_t quant(float x) {
    float v = (x + QOFFS) * QSCALE;
    v = fminf(fmaxf(v, 0.0f), 65535.0f);
    return (uint32_t)(v + 0.5f);
}

__global__ __launch_bounds__(THREADS, 8) void chamfer_partial_kernel(
    const float* __restrict__ pred, const float* __restrict__ target,
    uint32_t* __restrict__ wsmin)
{
    __shared__ __align__(16) uint2 tile[CHUNKPTS];   // 2 KiB

    const int t    = threadIdx.x;
    const int qg   = blockIdx.x >> 5;     // 0..7
    const int c    = blockIdx.x & 31;     // 0..31
    const int dirb = blockIdx.y;          // 0..7
    const int dir  = dirb >> 2;           // 0: pred->target, 1: target->pred
    const int b    = dirb & 3;

    const float* qbase = (dir == 0 ? pred : target) + (size_t)b * NPTS * 3;
    const float* rbase = (dir == 0 ? target : pred) + (size_t)b * NPTS * 3;

    // stage this block's 256-ref chunk, quantized+packed (1 pt/thread)
    {
        const float* rp = rbase + (size_t)(c * CHUNKPTS + t) * 3;
        tile[t] = make_uint2(quant(rp[0]) | (quant(rp[1]) << 16), quant(rp[2]));
    }

    // my 4 queries
    uint32_t qxy[QPL], qz[QPL], best[QPL];
    #pragma unroll
    for (int k = 0; k < QPL; ++k) {
        int q = qg * QPB + k * THREADS + t;
        const float* qp = qbase + (size_t)q * 3;
        qxy[k]  = quant(qp[0]) | (quant(qp[1]) << 16);
        qz[k]   = quant(qp[2]);
        best[k] = 0xFFFFFFFFu;
    }
    __syncthreads();

    // scan: one broadcast ds_read_b128 = 2 points, shared by 4 queries
    const uint4* tp = reinterpret_cast<const uint4*>(tile);
    #pragma unroll 4
    for (int j = 0; j < CHUNKPTS / 2; ++j) {
        uint4 v = tp[j];
        #pragma unroll
        for (int k = 0; k < QPL; ++k) {
            uint32_t d0 = sad_u16(v.y, qz[k], sad_u16(v.x, qxy[k], 0u));
            uint32_t d1 = sad_u16(v.w, qz[k], sad_u16(v.z, qxy[k], 0u));
            best[k] = min3_u32(d0, d1, best[k]);
        }
    }

    // fold this chunk's per-query mins into the global per-query min
    uint32_t* dst = wsmin + (size_t)dirb * NPTS + qg * QPB + t;
    #pragma unroll
    for (int k = 0; k < QPL; ++k)
        atomicMin(&dst[k * THREADS], best[k]);
}

__global__ __launch_bounds__(256) void chamfer_reduce_kernel(
    const uint32_t* __restrict__ wsmin, float* __restrict__ out)
{
    const int tid = blockIdx.x * 256 + threadIdx.x;   // 16384 threads
    uint4 v = reinterpret_cast<const uint4*>(wsmin)[tid];
    float fsum = (float)v.x + (float)v.y + (float)v.z + (float)v.w;
    #pragma unroll
    for (int off = 32; off > 0; off >>= 1)
        fsum += __shfl_down(fsum, off);
    if ((threadIdx.x & 63) == 0)
        atomicAdd(out, fsum * (1.0f / (QSCALE * (float)BATCH)));
}

extern "C" void kernel_launch(void* const* d_in, const int* in_sizes, int n_in,
                              void* d_out, int out_size, void* d_ws, size_t ws_size,
                              hipStream_t stream) {
    const float* pred   = (const float*)d_in[0];
    const float* target = (const float*)d_in[1];
    float* out = (float*)d_out;
    uint32_t* wsmin = (uint32_t*)d_ws;   // 8 dirb x 8192 x u32 = 256 KiB

    hipMemsetAsync(wsmin, 0xFF, (size_t)8 * NPTS * sizeof(uint32_t), stream);
    hipMemsetAsync(out, 0, sizeof(float), stream);

    dim3 grid(NQG * NCHUNK, 2 * BATCH);   // 256 x 8 = 2048 blocks, 8/CU
    chamfer_partial_kernel<<<grid, THREADS, 0, stream>>>(pred, target, wsmin);
    chamfer_reduce_kernel<<<64, 256, 0, stream>>>(wsmin, out);
}

// Round 4
// 54.497 us; speedup vs baseline: 1.0491x; 1.0025x over previous
//
#include <hip/hip_runtime.h>
#include <stdint.h>

// Chamfer L1, B=4, N=M=8192, 3-D points.
// u16 fixed-point quantization (4096/unit, +8 offset):
//   pair distance = 2x v_sad_u16 (half-rate: 4cyc), min via v_min3_u32.
// VALU floor = 8.39M wave-pairs x 9 cyc / 1024 SIMDs = 30.7 us.
// 2048 blocks (8/CU -> 8 waves/SIMD) to saturate VALU; per-chunk mins
// combined via global atomicMin into 256 KB ws, then a tiny sum kernel.

#define BATCH    4
#define NPTS     8192
#define QSCALE   4096.0f
#define QOFFS    8.0f
#define NCHUNK   32
#define CHUNKPTS (NPTS / NCHUNK)   // 256 refs per block
#define THREADS  256
#define QPL      4                 // queries per lane
#define QPB      (THREADS * QPL)   // 1024 queries per block
#define NQG      (NPTS / QPB)      // 8 query groups

static __device__ __forceinline__ uint32_t sad_u16(uint32_t a, uint32_t b, uint32_t c) {
#if __has_builtin(__builtin_amdgcn_sad_u16)
    return __builtin_amdgcn_sad_u16(a, b, c);
#else
    uint32_t d;
    asm("v_sad_u16 %0, %1, %2, %3" : "=v"(d) : "v"(a), "v"(b), "v"(c));
    return d;
#endif
}

static __device__ __forceinline__ uint32_t min3_u32(uint32_t a, uint32_t b, uint32_t c) {
    uint32_t d;
    asm("v_min3_u32 %0, %1, %2, %3" : "=v"(d) : "v"(a), "v"(b), "v"(c));
    return d;
}

static __device__ __forceinline__ uint32_t quant(float x) {
    float v = (x + QOFFS) * QSCALE;
    v = fminf(fmaxf(v, 0.0f), 65535.0f);
    return (uint32_t)(v + 0.5f);
}

__global__ __launch_bounds__(THREADS, 8) void chamfer_partial_kernel(
    const float* __restrict__ pred, const float* __restrict__ target,
    uint32_t* __restrict__ wsmin)
{
    __shared__ __align__(16) uint2 tile[CHUNKPTS];   // 2 KiB

    const int t    = threadIdx.x;
    const int qg   = blockIdx.x >> 5;     // 0..7
    const int c    = blockIdx.x & 31;     // 0..31
    const int dirb = blockIdx.y;          // 0..7
    const int dir  = dirb >> 2;           // 0: pred->target, 1: target->pred
    const int b    = dirb & 3;

    const float* qbase = (dir == 0 ? pred : target) + (size_t)b * NPTS * 3;
    const float* rbase = (dir == 0 ? target : pred) + (size_t)b * NPTS * 3;

    // stage this block's 256-ref chunk, quantized+packed (1 pt/thread)
    {
        const float* rp = rbase + (size_t)(c * CHUNKPTS + t) * 3;
        tile[t] = make_uint2(quant(rp[0]) | (quant(rp[1]) << 16), quant(rp[2]));
    }

    // my 4 queries
    uint32_t qxy[QPL], qz[QPL], best[QPL];
    #pragma unroll
    for (int k = 0; k < QPL; ++k) {
        int q = qg * QPB + k * THREADS + t;
        const float* qp = qbase + (size_t)q * 3;
        qxy[k]  = quant(qp[0]) | (quant(qp[1]) << 16);
        qz[k]   = quant(qp[2]);
        best[k] = 0xFFFFFFFFu;
    }
    __syncthreads();

    // scan: one broadcast ds_read_b128 = 2 points, shared by 4 queries
    const uint4* tp = reinterpret_cast<const uint4*>(tile);
    #pragma unroll 4
    for (int j = 0; j < CHUNKPTS / 2; ++j) {
        uint4 v = tp[j];
        #pragma unroll
        for (int k = 0; k < QPL; ++k) {
            uint32_t d0 = sad_u16(v.y, qz[k], sad_u16(v.x, qxy[k], 0u));
            uint32_t d1 = sad_u16(v.w, qz[k], sad_u16(v.z, qxy[k], 0u));
            best[k] = min3_u32(d0, d1, best[k]);
        }
    }

    // fold this chunk's per-query mins into the global per-query min
    uint32_t* dst = wsmin + (size_t)dirb * NPTS + qg * QPB + t;
    #pragma unroll
    for (int k = 0; k < QPL; ++k)
        atomicMin(&dst[k * THREADS], best[k]);
}

__global__ __launch_bounds__(256) void chamfer_reduce_kernel(
    const uint32_t* __restrict__ wsmin, float* __restrict__ out)
{
    const int tid = blockIdx.x * 256 + threadIdx.x;   // 16384 threads
    uint4 v = reinterpret_cast<const uint4*>(wsmin)[tid];
    float fsum = (float)v.x + (float)v.y + (float)v.z + (float)v.w;
    #pragma unroll
    for (int off = 32; off > 0; off >>= 1)
        fsum += __shfl_down(fsum, off);
    if ((threadIdx.x & 63) == 0)
        atomicAdd(out, fsum * (1.0f / (QSCALE * (float)BATCH)));
}

extern "C" void kernel_launch(void* const* d_in, const int* in_sizes, int n_in,
                              void* d_out, int out_size, void* d_ws, size_t ws_size,
                              hipStream_t stream) {
    const float* pred   = (const float*)d_in[0];
    const float* target = (const float*)d_in[1];
    float* out = (float*)d_out;
    uint32_t* wsmin = (uint32_t*)d_ws;   // 8 dirb x 8192 x u32 = 256 KiB

    hipMemsetAsync(wsmin, 0xFF, (size_t)8 * NPTS * sizeof(uint32_t), stream);
    hipMemsetAsync(out, 0, sizeof(float), stream);

    dim3 grid(NQG * NCHUNK, 2 * BATCH);   // 256 x 8 = 2048 blocks, 8/CU
    chamfer_partial_kernel<<<grid, THREADS, 0, stream>>>(pred, target, wsmin);
    chamfer_reduce_kernel<<<64, 256, 0, stream>>>(wsmin, out);
}

// Round 5
// 54.473 us; speedup vs baseline: 1.0496x; 1.0004x over previous
//
#include <hip/hip_runtime.h>
#include <stdint.h>

// Chamfer L1, B=4, N=M=8192, 3-D points.
// u16 fixed-point quantization (4096/unit, +8 offset):
//   pair distance = 2x v_sad_u16 (half-rate: 4cyc), min via v_min3_u32.
// VALU floor = 8.39M wave-pairs x 9 cyc / 1024 SIMDs = 30.7 us.
// 2048 blocks (8/CU -> 8 waves/SIMD) to saturate VALU; per-chunk mins
// combined via global atomicMin into 256 KB ws, then a tiny sum kernel.

#define BATCH    4
#define NPTS     8192
#define QSCALE   4096.0f
#define QOFFS    8.0f
#define NCHUNK   32
#define CHUNKPTS (NPTS / NCHUNK)   // 256 refs per block
#define THREADS  256
#define QPL      4                 // queries per lane
#define QPB      (THREADS * QPL)   // 1024 queries per block
#define NQG      (NPTS / QPB)      // 8 query groups

static __device__ __forceinline__ uint32_t sad_u16(uint32_t a, uint32_t b, uint32_t c) {
#if __has_builtin(__builtin_amdgcn_sad_u16)
    return __builtin_amdgcn_sad_u16(a, b, c);
#else
    uint32_t d;
    asm("v_sad_u16 %0, %1, %2, %3" : "=v"(d) : "v"(a), "v"(b), "v"(c));
    return d;
#endif
}

static __device__ __forceinline__ uint32_t min3_u32(uint32_t a, uint32_t b, uint32_t c) {
    uint32_t d;
    asm("v_min3_u32 %0, %1, %2, %3" : "=v"(d) : "v"(a), "v"(b), "v"(c));
    return d;
}

static __device__ __forceinline__ uint32_t quant(float x) {
    float v = (x + QOFFS) * QSCALE;
    v = fminf(fmaxf(v, 0.0f), 65535.0f);
    return (uint32_t)(v + 0.5f);
}

__global__ __launch_bounds__(THREADS, 8) void chamfer_partial_kernel(
    const float* __restrict__ pred, const float* __restrict__ target,
    uint32_t* __restrict__ wsmin)
{
    __shared__ __align__(16) uint2 tile[CHUNKPTS];   // 2 KiB

    const int t    = threadIdx.x;
    const int qg   = blockIdx.x >> 5;     // 0..7
    const int c    = blockIdx.x & 31;     // 0..31
    const int dirb = blockIdx.y;          // 0..7
    const int dir  = dirb >> 2;           // 0: pred->target, 1: target->pred
    const int b    = dirb & 3;

    const float* qbase = (dir == 0 ? pred : target) + (size_t)b * NPTS * 3;
    const float* rbase = (dir == 0 ? target : pred) + (size_t)b * NPTS * 3;

    // stage this block's 256-ref chunk, quantized+packed (1 pt/thread)
    {
        const float* rp = rbase + (size_t)(c * CHUNKPTS + t) * 3;
        tile[t] = make_uint2(quant(rp[0]) | (quant(rp[1]) << 16), quant(rp[2]));
    }

    // my 4 queries
    uint32_t qxy[QPL], qz[QPL], best[QPL];
    #pragma unroll
    for (int k = 0; k < QPL; ++k) {
        int q = qg * QPB + k * THREADS + t;
        const float* qp = qbase + (size_t)q * 3;
        qxy[k]  = quant(qp[0]) | (quant(qp[1]) << 16);
        qz[k]   = quant(qp[2]);
        best[k] = 0xFFFFFFFFu;
    }
    __syncthreads();

    // scan: one broadcast ds_read_b128 = 2 points, shared by 4 queries
    const uint4* tp = reinterpret_cast<const uint4*>(tile);
    #pragma unroll 4
    for (int j = 0; j < CHUNKPTS / 2; ++j) {
        uint4 v = tp[j];
        #pragma unroll
        for (int k = 0; k < QPL; ++k) {
            uint32_t d0 = sad_u16(v.y, qz[k], sad_u16(v.x, qxy[k], 0u));
            uint32_t d1 = sad_u16(v.w, qz[k], sad_u16(v.z, qxy[k], 0u));
            best[k] = min3_u32(d0, d1, best[k]);
        }
    }

    // fold this chunk's per-query mins into the global per-query min
    uint32_t* dst = wsmin + (size_t)dirb * NPTS + qg * QPB + t;
    #pragma unroll
    for (int k = 0; k < QPL; ++k)
        atomicMin(&dst[k * THREADS], best[k]);
}

__global__ __launch_bounds__(256) void chamfer_reduce_kernel(
    const uint32_t* __restrict__ wsmin, float* __restrict__ out)
{
    const int tid = blockIdx.x * 256 + threadIdx.x;   // 16384 threads
    uint4 v = reinterpret_cast<const uint4*>(wsmin)[tid];
    float fsum = (float)v.x + (float)v.y + (float)v.z + (float)v.w;
    #pragma unroll
    for (int off = 32; off > 0; off >>= 1)
        fsum += __shfl_down(fsum, off);
    if ((threadIdx.x & 63) == 0)
        atomicAdd(out, fsum * (1.0f / (QSCALE * (float)BATCH)));
}

extern "C" void kernel_launch(void* const* d_in, const int* in_sizes, int n_in,
                              void* d_out, int out_size, void* d_ws, size_t ws_size,
                              hipStream_t stream) {
    const float* pred   = (const float*)d_in[0];
    const float* target = (const float*)d_in[1];
    float* out = (float*)d_out;
    uint32_t* wsmin = (uint32_t*)d_ws;   // 8 dirb x 8192 x u32 = 256 KiB

    hipMemsetAsync(wsmin, 0xFF, (size_t)8 * NPTS * sizeof(uint32_t), stream);
    hipMemsetAsync(out, 0, sizeof(float), stream);

    dim3 grid(NQG * NCHUNK, 2 * BATCH);   // 256 x 8 = 2048 blocks, 8/CU
    chamfer_partial_kernel<<<grid, THREADS, 0, stream>>>(pred, target, wsmin);
    chamfer_reduce_kernel<<<64, 256, 0, stream>>>(wsmin, out);
}